// Round 3
// baseline (192.247 us; speedup 1.0000x reference)
//
#include <hip/hip_runtime.h>

using short8   = __attribute__((ext_vector_type(8))) short;
using f32x4    = __attribute__((ext_vector_type(4))) float;
using ushort4v = __attribute__((ext_vector_type(4))) unsigned short;

#define BN_EPS 1e-5f
// log2(e)/sqrt(32): folded into q projection so softmax uses native exp2
#define ATT_SCALE_LOG2E 0.2550348347988049f

__device__ __forceinline__ unsigned short f2bf(float f) {
    union { float f; unsigned u; } v; v.f = f;
    return (unsigned short)((v.u + 0x7FFFu + ((v.u >> 16) & 1u)) >> 16);  // RNE
}

// pack two f32 -> two bf16 (round-half-up): a in low 16, b in high 16
__device__ __forceinline__ unsigned pack2bf(float a, float b) {
    union { float f; unsigned u; } ua, ub; ua.f = a; ub.f = b;
    return __builtin_amdgcn_perm(ub.u + 0x8000u, ua.u + 0x8000u, 0x07060302u);
}

// ---------------------------------------------------------------------------
// Kernel 0: weights -> bf16; fold conv-bias + BN into per-row (scale, offset).
// Rows: 0-31 q, 32-63 k, 64-319 v.
// ---------------------------------------------------------------------------
__global__ void prep_kernel(
    const float* __restrict__ qw, const float* __restrict__ qb,
    const float* __restrict__ qg, const float* __restrict__ qbe,
    const float* __restrict__ qm, const float* __restrict__ qv,
    const float* __restrict__ kw, const float* __restrict__ kb,
    const float* __restrict__ kg, const float* __restrict__ kbe,
    const float* __restrict__ km, const float* __restrict__ kvv,
    const float* __restrict__ vw, const float* __restrict__ vb,
    const float* __restrict__ vg, const float* __restrict__ vbe,
    const float* __restrict__ vm, const float* __restrict__ vv,
    unsigned short* __restrict__ wq, float* __restrict__ scale,
    float* __restrict__ off)
{
    int r = blockIdx.x;      // 0..319
    int t = threadIdx.x;     // 0..63
    const float *wsrc, *g, *be, *mn, *vr, *bi;
    int rl;
    if (r < 32)      { rl = r;      wsrc = qw; g = qg; be = qbe; mn = qm; vr = qv;  bi = qb; }
    else if (r < 64) { rl = r - 32; wsrc = kw; g = kg; be = kbe; mn = km; vr = kvv; bi = kb; }
    else             { rl = r - 64; wsrc = vw; g = vg; be = vbe; mn = vm; vr = vv;  bi = vb; }

    float4 w4 = *(const float4*)(wsrc + rl * 256 + t * 4);
    ushort4v o;
    o.x = f2bf(w4.x); o.y = f2bf(w4.y); o.z = f2bf(w4.z); o.w = f2bf(w4.w);
    *(ushort4v*)(wq + r * 256 + t * 4) = o;

    if (t == 0) {
        float inv = g[rl] * rsqrtf(vr[rl] + BN_EPS);
        float ofv = bi[rl] * inv + be[rl] - mn[rl] * inv;
        float s = (r < 32) ? ATT_SCALE_LOG2E : 1.0f;
        scale[r] = inv * s;
        off[r]   = ofv * s;
    }
}

// ---------------------------------------------------------------------------
// Kernel 1: projections. bx>>8 = g: 0: q(x1), 1: k(x2), 2: v ALL 256 rows (x2).
// q_t/k_t: [b][n][32] bf16.  v_ws: TILE-BLOCKED [b*64+nt][256][64] bf16.
// ---------------------------------------------------------------------------
#define XT_PITCH 264

__global__ __launch_bounds__(256, 4) void proj_kernel(
    const float* __restrict__ x1, const float* __restrict__ x2,
    const unsigned short* __restrict__ wq,
    const float* __restrict__ scale, const float* __restrict__ off,
    unsigned short* __restrict__ q_t, unsigned short* __restrict__ k_t,
    unsigned short* __restrict__ v_ws)
{
    __shared__ __align__(16) unsigned short Xt[64 * XT_PITCH];   // 33792 B
    int bx = blockIdx.x;
    int g  = bx >> 8;        // 0,1,2
    int t2 = bx & 255;
    int nt = t2 & 63;
    int b  = t2 >> 6;
    int n0 = nt * 64;
    int tid = threadIdx.x;
    int wv = tid >> 6, lane = tid & 63;
    int m16 = lane & 15, qd = lane >> 4;

    const float* xb = ((g == 0) ? x1 : x2) + (size_t)b * 256 * 4096 + n0 + lane;

    // octet-gather transpose: n = lane, channels 8*o..8*o+7, o = wv*8+i
    #pragma unroll 2
    for (int i = 0; i < 8; ++i) {
        int o = wv * 8 + i;                       // 0..31
        const float* src = xb + (size_t)(o * 8) * 4096;
        uint4 dw;
        dw.x = pack2bf(src[0],                src[(size_t)1 * 4096]);
        dw.y = pack2bf(src[(size_t)2 * 4096], src[(size_t)3 * 4096]);
        dw.z = pack2bf(src[(size_t)4 * 4096], src[(size_t)5 * 4096]);
        dw.w = pack2bf(src[(size_t)6 * 4096], src[(size_t)7 * 4096]);
        *(uint4*)&Xt[lane * XT_PITCH + o * 8] = dw;
    }
    __syncthreads();

    f32x4 zero4 = {0.f, 0.f, 0.f, 0.f};

    if (g < 2) {
        int rb = g * 32;
        f32x4 acc0 = zero4, acc1 = zero4;
        #pragma unroll 2
        for (int s = 0; s < 8; ++s) {
            short8 w0 = *(const short8*)(wq + (size_t)(rb +      m16) * 256 + s * 32 + qd * 8);
            short8 w1 = *(const short8*)(wq + (size_t)(rb + 16 + m16) * 256 + s * 32 + qd * 8);
            short8 xf = *(const short8*)&Xt[(16 * wv + m16) * XT_PITCH + s * 32 + qd * 8];
            acc0 = __builtin_amdgcn_mfma_f32_16x16x32_bf16(w0, xf, acc0, 0, 0, 0);
            acc1 = __builtin_amdgcn_mfma_f32_16x16x32_bf16(w1, xf, acc1, 0, 0, 0);
        }
        unsigned short* dst = (g == 0) ? q_t : k_t;
        int ncol = n0 + 16 * wv + m16;
        #pragma unroll
        for (int tm = 0; tm < 2; ++tm) {
            f32x4 acc = tm ? acc1 : acc0;
            int r0 = 16 * tm + 4 * qd;
            float4 sc = *(const float4*)(scale + rb + r0);
            float4 of = *(const float4*)(off   + rb + r0);
            ushort4v o;
            o.x = f2bf(acc.x * sc.x + of.x);
            o.y = f2bf(acc.y * sc.y + of.y);
            o.z = f2bf(acc.z * sc.z + of.z);
            o.w = f2bf(acc.w * sc.w + of.w);
            *(ushort4v*)(dst + ((size_t)b * 4096 + ncol) * 32 + r0) = o;
        }
    } else {
        // v: all 256 rows from one x2 transpose
        f32x4 acc[4][4];
        #pragma unroll
        for (int rr = 0; rr < 4; ++rr)
            #pragma unroll
            for (int tm = 0; tm < 4; ++tm) acc[rr][tm] = zero4;
        #pragma unroll 1
        for (int s = 0; s < 8; ++s) {
            short8 xf[4];
            #pragma unroll
            for (int tm = 0; tm < 4; ++tm)
                xf[tm] = *(const short8*)&Xt[(16 * tm + m16) * XT_PITCH + s * 32 + qd * 8];
            #pragma unroll
            for (int rr = 0; rr < 4; ++rr) {
                short8 wf = *(const short8*)(wq + (size_t)(64 + rr * 64 + 16 * wv + m16) * 256 + s * 32 + qd * 8);
                #pragma unroll
                for (int tm = 0; tm < 4; ++tm)
                    acc[rr][tm] = __builtin_amdgcn_mfma_f32_16x16x32_bf16(xf[tm], wf, acc[rr][tm], 0, 0, 0);
            }
        }
        unsigned short* vt = v_ws + (size_t)(b * 64 + nt) * 256 * 64;
        #pragma unroll
        for (int rr = 0; rr < 4; ++rr) {
            int c = rr * 64 + 16 * wv + m16;
            float sc = scale[64 + c], of = off[64 + c];
            #pragma unroll
            for (int tm = 0; tm < 4; ++tm) {
                int nloc = 16 * tm + 4 * qd;
                ushort4v o;
                o.x = f2bf(acc[rr][tm].x * sc + of);
                o.y = f2bf(acc[rr][tm].y * sc + of);
                o.z = f2bf(acc[rr][tm].z * sc + of);
                o.w = f2bf(acc[rr][tm].w * sc + of);
                *(ushort4v*)(vt + c * 64 + nloc) = o;
            }
        }
    }
}

// ---------------------------------------------------------------------------
// Kernel 2: flash attention v3 — ZERO STAGING. Same structure as v2 (4-wave
// blocks, 64q x 128c, grid 512, 2 blk/CU, XCD-bijective (cg,b) mapping) but
// K/V MFMA fragments are loaded DIRECTLY from global into registers, double-
// buffered one iteration ahead (A/B register sets, hand-unrolled x2 so all
// indices are compile-time). Rationale: each V 16B chunk is consumed by
// exactly one wave and K rows are contiguous in k_t (1KB coalesced wave
// load), so LDS staging added a pure 40KB/blk/iter write+read round-trip
// with zero L2-traffic benefit. LDS keeps only the P round-trip (8KB) +
// Lsh (1KB). Barriers: B1 = plain s_barrier (P WAR fence; no vmcnt drain
// anywhere in the loop), B2 = lgkmcnt(0) + s_barrier (P visibility).
// ---------------------------------------------------------------------------
__global__ __launch_bounds__(256, 2) void flash_kernel(
    const unsigned short* __restrict__ q_t, const unsigned short* __restrict__ k_t,
    const unsigned short* __restrict__ v_ws, float* __restrict__ out)
{
    __shared__ __align__(16) unsigned short Ps[64 * 64];   // 8 KB
    __shared__ __align__(16) float Lsh[256];               // 1 KB

    int bx = blockIdx.x;                   // 512 blocks
    int cg = (bx >> 2) & 1;
    int b  = bx & 3;
    int qg = bx >> 3;                      // 0..63
    int q0 = qg * 64;
    int cb = cg * 128;

    int tid = threadIdx.x;
    int wv  = tid >> 6, lane = tid & 63;
    int m16 = lane & 15, qd = lane >> 4;
    int sw7 = m16 & 7;

    // ---- global fragment bases (per-lane) ----
    // K: [b][k][32]; wave wv owns key rows wv*16..+15 -> 1KB coalesced load
    const unsigned short* kbase = k_t + ((size_t)b * 4096 + wv * 16 + m16) * 32 + qd * 8;
    // V: tile-blocked [b*64+it][256][64]; wave wv owns channels wv*32..+31
    const unsigned short* vbase = v_ws + (size_t)b * 1048576
                                + (size_t)(cb + wv * 32 + m16) * 64 + qd * 8;

    // ---- persistent Q fragments (all 4 q-tiles) ----
    const unsigned short* qb = q_t + ((size_t)b * 4096 + q0) * 32;
    short8 Qf[4];
    #pragma unroll
    for (int qt = 0; qt < 4; ++qt)
        Qf[qt] = *(const short8*)(qb + (size_t)(qt * 16 + m16) * 32 + qd * 8);

    // ---- P LDS offsets (same verified swizzle as v2) ----
    int widx[4];
    #pragma unroll
    for (int qt = 0; qt < 4; ++qt)
        widx[qt] = (qt * 16 + m16) * 64 + (((wv * 2 + (qd >> 1)) ^ sw7) << 3) + ((qd & 1) << 2);
    int apo[4][2];
    #pragma unroll
    for (int qt = 0; qt < 4; ++qt)
        #pragma unroll
        for (int kc = 0; kc < 2; ++kc)
            apo[qt][kc] = (qt * 16 + m16) * 64 + (((kc * 4 + qd) ^ sw7) << 3);

    f32x4 zero4 = {0.f, 0.f, 0.f, 0.f};
    f32x4 acc[4][2];
    #pragma unroll
    for (int qt = 0; qt < 4; ++qt)
        #pragma unroll
        for (int ct = 0; ct < 2; ++ct) acc[qt][ct] = zero4;
    float lsum[4] = {0.f, 0.f, 0.f, 0.f};

    // ---- double-buffered fragment registers ----
    short8 KA, KB, VA[2][2], VB[2][2];
    KA = *(const short8*)kbase;                       // tile 0
    #pragma unroll
    for (int ct = 0; ct < 2; ++ct)
        #pragma unroll
        for (int kc = 0; kc < 2; ++kc)
            VA[ct][kc] = *(const short8*)(vbase + ct * 1024 + kc * 32);

    // one loop body: consume (Kc,Vc) for tile it; prefetch (Kn,Vn) for nx
    auto body = [&](short8& Kc, short8 (&Vc)[2][2],
                    short8& Kn, short8 (&Vn)[2][2], int nx) {
        // B1: all waves' Ap reads of the previous P are retired (they fed
        // MFMAs pre-barrier) -> safe to overwrite P this iteration.
        asm volatile("s_barrier" ::: "memory");

        // prefetch tile nx fragments (consumed one full iteration later)
        Kn = *(const short8*)(kbase + (size_t)nx * 2048);
        #pragma unroll
        for (int ct = 0; ct < 2; ++ct)
            #pragma unroll
            for (int kc = 0; kc < 2; ++kc)
                Vn[ct][kc] = *(const short8*)(vbase + (size_t)nx * 16384 + ct * 1024 + kc * 32);

        // ---- QK: S^T (16k x 16q) per q-tile; k = wv*16 + 4*qd + r ----
        #pragma unroll
        for (int qt = 0; qt < 4; ++qt) {
            f32x4 S = __builtin_amdgcn_mfma_f32_16x16x32_bf16(Kc, Qf[qt], zero4, 0, 0, 0);
            float a0 = __builtin_amdgcn_exp2f(S.x), a1 = __builtin_amdgcn_exp2f(S.y);
            float a2 = __builtin_amdgcn_exp2f(S.z), a3 = __builtin_amdgcn_exp2f(S.w);
            lsum[qt] += (a0 + a1) + (a2 + a3);
            uint2 w; w.x = pack2bf(a0, a1); w.y = pack2bf(a2, a3);
            *(uint2*)&Ps[widx[qt]] = w;
        }

        // B2: P visible to all waves; no vmcnt drain (prefetch stays in flight)
        asm volatile("s_waitcnt lgkmcnt(0)\n\ts_barrier" ::: "memory");

        __builtin_amdgcn_s_setprio(1);
        short8 Ap[4][2];
        #pragma unroll
        for (int qt = 0; qt < 4; ++qt)
            #pragma unroll
            for (int kc = 0; kc < 2; ++kc)
                Ap[qt][kc] = *(const short8*)&Ps[apo[qt][kc]];
        #pragma unroll
        for (int qt = 0; qt < 4; ++qt)
            #pragma unroll
            for (int ct = 0; ct < 2; ++ct) {
                acc[qt][ct] = __builtin_amdgcn_mfma_f32_16x16x32_bf16(Ap[qt][0], Vc[ct][0], acc[qt][ct], 0, 0, 0);
                acc[qt][ct] = __builtin_amdgcn_mfma_f32_16x16x32_bf16(Ap[qt][1], Vc[ct][1], acc[qt][ct], 0, 0, 0);
            }
        __builtin_amdgcn_s_setprio(0);
    };

    #pragma unroll 1
    for (int it = 0; it < 64; it += 2) {
        body(KA, VA, KB, VB, it + 1);                           // even: it
        body(KB, VB, KA, VA, (it + 2 > 63) ? 63 : it + 2);      // odd: it+1
    }

    // ---- softmax denominators: qd-reduce in-wave, key-slice combine in LDS ----
    #pragma unroll
    for (int qt = 0; qt < 4; ++qt) {
        float l = lsum[qt];
        l += __shfl_xor(l, 16);
        l += __shfl_xor(l, 32);
        if (lane < 16) Lsh[wv * 64 + qt * 16 + lane] = l;
    }
    asm volatile("s_waitcnt lgkmcnt(0)\n\ts_barrier" ::: "memory");

    #pragma unroll
    for (int qt = 0; qt < 4; ++qt) {
        f32x4 s4 = *(const f32x4*)&Lsh[qt * 16 + qd * 4];
        s4 += *(const f32x4*)&Lsh[64  + qt * 16 + qd * 4];
        s4 += *(const f32x4*)&Lsh[128 + qt * 16 + qd * 4];
        s4 += *(const f32x4*)&Lsh[192 + qt * 16 + qd * 4];
        f32x4 inv4;
        inv4.x = __builtin_amdgcn_rcpf(s4.x);
        inv4.y = __builtin_amdgcn_rcpf(s4.y);
        inv4.z = __builtin_amdgcn_rcpf(s4.z);
        inv4.w = __builtin_amdgcn_rcpf(s4.w);
        #pragma unroll
        for (int ct = 0; ct < 2; ++ct) {
            // acc: col=m16=c-local, row=4*qd+r=q-local
            float* ob = out + ((size_t)(b * 256 + cb + wv * 32 + ct * 16 + m16)) * 4096
                            + q0 + qt * 16 + qd * 4;
            float4 o;
            o.x = acc[qt][ct].x * inv4.x;
            o.y = acc[qt][ct].y * inv4.y;
            o.z = acc[qt][ct].z * inv4.z;
            o.w = acc[qt][ct].w * inv4.w;
            *(float4*)ob = o;
        }
    }
}

// ---------------------------------------------------------------------------
// Workspace: wq 320x256 bf16 | scale/off 320 f32 | q_t,k_t [b][n][32] bf16 |
// v_ws tile-blocked [b*64+kt][256][64] bf16. Total ~10.7 MB.
// ---------------------------------------------------------------------------
extern "C" void kernel_launch(void* const* d_in, const int* in_sizes, int n_in,
                              void* d_out, int out_size, void* d_ws, size_t ws_size,
                              hipStream_t stream)
{
    const float* x1  = (const float*)d_in[0];
    const float* x2  = (const float*)d_in[1];
    const float* qw  = (const float*)d_in[2];
    const float* qb  = (const float*)d_in[3];
    const float* qg  = (const float*)d_in[4];
    const float* qbe = (const float*)d_in[5];
    const float* qm  = (const float*)d_in[6];
    const float* qv  = (const float*)d_in[7];
    const float* kw  = (const float*)d_in[8];
    const float* kb  = (const float*)d_in[9];
    const float* kg  = (const float*)d_in[10];
    const float* kbe = (const float*)d_in[11];
    const float* km  = (const float*)d_in[12];
    const float* kvv = (const float*)d_in[13];
    const float* vw  = (const float*)d_in[14];
    const float* vb  = (const float*)d_in[15];
    const float* vg  = (const float*)d_in[16];
    const float* vbe = (const float*)d_in[17];
    const float* vm  = (const float*)d_in[18];
    const float* vv  = (const float*)d_in[19];

    char* ws = (char*)d_ws;
    unsigned short* wq   = (unsigned short*)(ws + 0);
    float*          scale= (float*)(ws + 163840);
    float*          off  = (float*)(ws + 165120);
    unsigned short* q_t  = (unsigned short*)(ws + 166400);
    unsigned short* k_t  = (unsigned short*)(ws + 166400 + 1048576);
    unsigned short* v_ws = (unsigned short*)(ws + 166400 + 2097152);

    prep_kernel<<<320, 64, 0, stream>>>(qw, qb, qg, qbe, qm, qv,
                                        kw, kb, kg, kbe, km, kvv,
                                        vw, vb, vg, vbe, vm, vv,
                                        wq, scale, off);
    proj_kernel<<<768, 256, 0, stream>>>(x1, x2, wq, scale, off, q_t, k_t, v_ws);
    flash_kernel<<<512, 256, 0, stream>>>(q_t, k_t, v_ws, (float*)d_out);
}